// Round 1
// baseline (7389.285 us; speedup 1.0000x reference)
//
#include <hip/hip_runtime.h>
#include <cstdint>
#include <cstddef>

#define NPTS 262144
#define BLK 256
#define TGX 176
#define TGY 200
#define TGZ 1

#define SCAN_ITEMS 32
#define SCAN_CHUNK (BLK*SCAN_ITEMS)

// ---------------- voxel coord helpers ----------------
__device__ __forceinline__ void pcoords(float x, float y, float z,
    float vx, float vy, float vz, int gx, int gy, int gz,
    int& cx, int& cy, int& cz) {
  cx = (int)floorf((x - 0.0f)  / vx);
  cy = (int)floorf((y + 40.0f) / vy);
  cz = (int)floorf((z + 3.0f)  / vz);
  cx = min(max(cx, 0), gx - 1);
  cy = min(max(cy, 0), gy - 1);
  cz = min(max(cz, 0), gz - 1);
}

// ---------------- pass 1: dense count grid ----------------
__global__ __launch_bounds__(BLK) void k_count(const float* __restrict__ pts,
    int* __restrict__ cnt, int gx, int gy, int gz, float vx, float vy, float vz) {
  int i = blockIdx.x * BLK + threadIdx.x;
  if (i >= NPTS) return;
  float b = pts[i*5+0], x = pts[i*5+1], y = pts[i*5+2], z = pts[i*5+3];
  int cx, cy, cz; pcoords(x, y, z, vx, vy, vz, gx, gy, gz, cx, cy, cz);
  int lin = (((int)b * gz + cz) * gy + cy) * gx + cx;
  atomicAdd(&cnt[lin], 1);
}

// ---------------- occupancy scan (3 phases) ----------------
__global__ __launch_bounds__(BLK) void k_scan1(const int* __restrict__ cnt, int G,
                                               int* __restrict__ bsum) {
  int base = blockIdx.x * SCAN_CHUNK + threadIdx.x * SCAN_ITEMS;
  int s = 0;
  #pragma unroll
  for (int k = 0; k < SCAN_ITEMS; k++) {
    int j = base + k;
    if (j < G && cnt[j] > 0) s++;
  }
  __shared__ int sh[BLK];
  sh[threadIdx.x] = s; __syncthreads();
  for (int off = BLK/2; off > 0; off >>= 1) {
    if (threadIdx.x < off) sh[threadIdx.x] += sh[threadIdx.x + off];
    __syncthreads();
  }
  if (threadIdx.x == 0) bsum[blockIdx.x] = sh[0];
}

__global__ __launch_bounds__(1024) void k_scan2(int* __restrict__ bsum, int nb,
                                                int* __restrict__ U) {
  __shared__ int sh[1024];
  int t = threadIdx.x;
  int v0 = (t < nb) ? bsum[t] : 0;
  sh[t] = v0; __syncthreads();
  for (int off = 1; off < 1024; off <<= 1) {
    int v = (t >= off) ? sh[t - off] : 0;
    __syncthreads();
    sh[t] += v;
    __syncthreads();
  }
  if (t < nb) bsum[t] = sh[t] - v0;   // exclusive
  if (t == 0) *U = sh[1023];          // total occupied
}

__global__ __launch_bounds__(BLK) void k_scan3(const int* __restrict__ cnt, int G,
    const int* __restrict__ bsum, int* __restrict__ rank, int* __restrict__ uniq) {
  int base = blockIdx.x * SCAN_CHUNK + threadIdx.x * SCAN_ITEMS;
  unsigned mask = 0;
  #pragma unroll
  for (int k = 0; k < SCAN_ITEMS; k++) {
    int j = base + k;
    if (j < G && cnt[j] > 0) mask |= (1u << k);
  }
  int s = __popc(mask);
  __shared__ int sh[BLK];
  sh[threadIdx.x] = s; __syncthreads();
  for (int off = 1; off < BLK; off <<= 1) {
    int v = (threadIdx.x >= off) ? sh[threadIdx.x - off] : 0;
    __syncthreads();
    sh[threadIdx.x] += v;
    __syncthreads();
  }
  int run = bsum[blockIdx.x] + sh[threadIdx.x] - s;
  #pragma unroll
  for (int k = 0; k < SCAN_ITEMS; k++) {
    if (mask & (1u << k)) {
      int j = base + k;
      rank[j] = run;
      uniq[run] = j;
      run++;
    }
  }
}

// ---------------- xyz sums per voxel (compact by rank) ----------------
__global__ __launch_bounds__(BLK) void k_xyzsum(const float* __restrict__ pts,
    const int* __restrict__ rank, float* __restrict__ sxyz,
    int gx, int gy, int gz, float vx, float vy, float vz) {
  int i = blockIdx.x * BLK + threadIdx.x;
  if (i >= NPTS) return;
  float b = pts[i*5+0], x = pts[i*5+1], y = pts[i*5+2], z = pts[i*5+3];
  int cx, cy, cz; pcoords(x, y, z, vx, vy, vz, gx, gy, gz, cx, cy, cz);
  int lin = (((int)b * gz + cz) * gy + cy) * gx + cx;
  int r = rank[lin];
  atomicAdd(&sxyz[r*3+0], x);
  atomicAdd(&sxyz[r*3+1], y);
  atomicAdd(&sxyz[r*3+2], z);
}

// ---------------- layer 1 matmul: feats(10) @ W1 -> Y (N x C1) ----------------
template<int C1>
__global__ __launch_bounds__(BLK) void k_y1(const float* __restrict__ pts,
    const int* __restrict__ cnt, const int* __restrict__ rank,
    const float* __restrict__ sxyz, const float* __restrict__ W1,
    float* __restrict__ Y, int gx, int gy, int gz, float vx, float vy, float vz) {
  __shared__ float w[10*C1];
  for (int t = threadIdx.x; t < 10*C1; t += BLK) w[t] = W1[t];
  __syncthreads();
  int i = blockIdx.x * BLK + threadIdx.x;
  if (i >= NPTS) return;
  float b = pts[i*5+0], x = pts[i*5+1], y = pts[i*5+2], z = pts[i*5+3], it = pts[i*5+4];
  int cx, cy, cz; pcoords(x, y, z, vx, vy, vz, gx, gy, gz, cx, cy, cz);
  int lin = (((int)b * gz + cz) * gy + cy) * gx + cx;
  int r = rank[lin];
  float ic = 1.0f / (float)cnt[lin];
  float f[10];
  f[0] = x; f[1] = y; f[2] = z; f[3] = it;
  f[4] = x - sxyz[r*3+0]*ic;
  f[5] = y - sxyz[r*3+1]*ic;
  f[6] = z - sxyz[r*3+2]*ic;
  f[7] = x - (0.0f   + (cx + 0.5f)*vx);
  f[8] = y - (-40.0f + (cy + 0.5f)*vy);
  f[9] = z - (-3.0f  + (cz + 0.5f)*vz);
  float* yo = &Y[(size_t)i*C1];
  #pragma unroll
  for (int o = 0; o < C1; o += 4) {
    float a0=0.f, a1=0.f, a2=0.f, a3=0.f;
    #pragma unroll
    for (int k = 0; k < 10; k++) {
      float fv = f[k];
      const float* wr = &w[k*C1 + o];
      a0 = fmaf(fv, wr[0], a0); a1 = fmaf(fv, wr[1], a1);
      a2 = fmaf(fv, wr[2], a2); a3 = fmaf(fv, wr[3], a3);
    }
    float4 v = {a0, a1, a2, a3};
    *(float4*)&yo[o] = v;
  }
}

// ---------------- column sum/sumsq reduction ----------------
template<int C>
__global__ __launch_bounds__(BLK) void k_colreduce(const float* __restrict__ Y,
    float* __restrict__ stats, int rowsPerBlock) {
  constexpr int G = BLK / C;
  int c = threadIdx.x & (C - 1);
  int g = threadIdx.x / C;
  int i0 = blockIdx.x * rowsPerBlock;
  float s = 0.f, q = 0.f;
  for (int rr = g; rr < rowsPerBlock; rr += G) {
    float v = Y[(size_t)(i0 + rr)*C + c];
    s += v; q += v*v;
  }
  __shared__ float ss[BLK], sq[BLK];
  ss[threadIdx.x] = s; sq[threadIdx.x] = q;
  __syncthreads();
  for (int off = BLK/2; off >= C; off >>= 1) {
    if (threadIdx.x < off) {
      ss[threadIdx.x] += ss[threadIdx.x + off];
      sq[threadIdx.x] += sq[threadIdx.x + off];
    }
    __syncthreads();
  }
  if (threadIdx.x < C) {
    atomicAdd(&stats[c], ss[threadIdx.x]);
    atomicAdd(&stats[C + c], sq[threadIdx.x]);
  }
}

template<int C>
__global__ void k_bncoef(const float* __restrict__ stats, const float* __restrict__ g,
                         const float* __restrict__ b, float* __restrict__ coef) {
  int c = threadIdx.x;
  if (c >= C) return;
  float mu  = stats[c] * (1.0f / NPTS);
  float var = stats[C + c] * (1.0f / NPTS) - mu*mu;
  float sc  = g[c] * (1.0f / sqrtf(var + 1e-3f));
  coef[c]     = sc;
  coef[C + c] = fmaf(-mu, sc, b[c]);
}

// ---------------- BN + ReLU + segment-sum scatter ----------------
template<int C, bool WRITE_H>
__global__ __launch_bounds__(BLK) void k_bnseg(const float* __restrict__ pts,
    float* __restrict__ Y, const float* __restrict__ coef,
    const int* __restrict__ rank, float* __restrict__ seg,
    int gx, int gy, int gz, float vx, float vy, float vz) {
  __shared__ float sc[C], sb[C];
  for (int t = threadIdx.x; t < C; t += BLK) { sc[t] = coef[t]; sb[t] = coef[C + t]; }
  __syncthreads();
  int i = blockIdx.x * BLK + threadIdx.x;
  if (i >= NPTS) return;
  float b = pts[i*5+0], x = pts[i*5+1], y = pts[i*5+2], z = pts[i*5+3];
  int cx, cy, cz; pcoords(x, y, z, vx, vy, vz, gx, gy, gz, cx, cy, cz);
  int lin = (((int)b * gz + cz) * gy + cy) * gx + cx;
  int r = rank[lin];
  float* yr = &Y[(size_t)i*C];
  float* sr = &seg[(size_t)r*C];
  #pragma unroll
  for (int o = 0; o < C; o += 4) {
    float4 v = *(float4*)&yr[o];
    float h0 = fmaxf(fmaf(v.x, sc[o+0], sb[o+0]), 0.f);
    float h1 = fmaxf(fmaf(v.y, sc[o+1], sb[o+1]), 0.f);
    float h2 = fmaxf(fmaf(v.z, sc[o+2], sb[o+2]), 0.f);
    float h3 = fmaxf(fmaf(v.w, sc[o+3], sb[o+3]), 0.f);
    if (WRITE_H) { float4 hh = {h0, h1, h2, h3}; *(float4*)&yr[o] = hh; }
    atomicAdd(&sr[o+0], h0);
    atomicAdd(&sr[o+1], h1);
    atomicAdd(&sr[o+2], h2);
    atomicAdd(&sr[o+3], h3);
  }
}

// ---------------- layer 2: [h1, segmean1] @ W2 -> Y2 (N x C2) ----------------
template<int C1>
__global__ __launch_bounds__(BLK) void k_y2(const float* __restrict__ pts,
    const float* __restrict__ H1, const float* __restrict__ seg1,
    const int* __restrict__ cnt, const int* __restrict__ rank,
    const float* __restrict__ W2, float* __restrict__ Y2,
    int gx, int gy, int gz, float vx, float vy, float vz) {
  constexpr int C2 = 2 * C1;
  __shared__ float w[2*C1*C2];
  for (int t = threadIdx.x*4; t < 2*C1*C2; t += BLK*4)
    *(float4*)&w[t] = *(const float4*)&W2[t];
  __syncthreads();
  int i = blockIdx.x * BLK + threadIdx.x;
  if (i >= NPTS) return;
  float b = pts[i*5+0], x = pts[i*5+1], y = pts[i*5+2], z = pts[i*5+3];
  int cx, cy, cz; pcoords(x, y, z, vx, vy, vz, gx, gy, gz, cx, cy, cz);
  int lin = (((int)b * gz + cz) * gy + cy) * gx + cx;
  int r = rank[lin];
  float ic = 1.0f / (float)cnt[lin];
  const float* h1row = &H1[(size_t)i*C1];
  const float* smrow = &seg1[(size_t)r*C1];
  #pragma unroll 1
  for (int oc = 0; oc < C2; oc += 16) {
    float acc[16];
    #pragma unroll
    for (int j = 0; j < 16; j++) acc[j] = 0.f;
    for (int k = 0; k < C1; k += 4) {
      float4 a = *(const float4*)&h1row[k];
      float av[4] = {a.x, a.y, a.z, a.w};
      #pragma unroll
      for (int kk = 0; kk < 4; kk++) {
        const float* wr = &w[(k + kk)*C2 + oc];
        float4 w0 = *(float4*)&wr[0],  w1 = *(float4*)&wr[4];
        float4 w2 = *(float4*)&wr[8],  w3 = *(float4*)&wr[12];
        float fv = av[kk];
        acc[0]  = fmaf(fv, w0.x, acc[0]);  acc[1]  = fmaf(fv, w0.y, acc[1]);
        acc[2]  = fmaf(fv, w0.z, acc[2]);  acc[3]  = fmaf(fv, w0.w, acc[3]);
        acc[4]  = fmaf(fv, w1.x, acc[4]);  acc[5]  = fmaf(fv, w1.y, acc[5]);
        acc[6]  = fmaf(fv, w1.z, acc[6]);  acc[7]  = fmaf(fv, w1.w, acc[7]);
        acc[8]  = fmaf(fv, w2.x, acc[8]);  acc[9]  = fmaf(fv, w2.y, acc[9]);
        acc[10] = fmaf(fv, w2.z, acc[10]); acc[11] = fmaf(fv, w2.w, acc[11]);
        acc[12] = fmaf(fv, w3.x, acc[12]); acc[13] = fmaf(fv, w3.y, acc[13]);
        acc[14] = fmaf(fv, w3.z, acc[14]); acc[15] = fmaf(fv, w3.w, acc[15]);
      }
    }
    for (int k = 0; k < C1; k += 4) {
      float4 a = *(const float4*)&smrow[k];
      float av[4] = {a.x*ic, a.y*ic, a.z*ic, a.w*ic};
      #pragma unroll
      for (int kk = 0; kk < 4; kk++) {
        const float* wr = &w[(C1 + k + kk)*C2 + oc];
        float4 w0 = *(float4*)&wr[0],  w1 = *(float4*)&wr[4];
        float4 w2 = *(float4*)&wr[8],  w3 = *(float4*)&wr[12];
        float fv = av[kk];
        acc[0]  = fmaf(fv, w0.x, acc[0]);  acc[1]  = fmaf(fv, w0.y, acc[1]);
        acc[2]  = fmaf(fv, w0.z, acc[2]);  acc[3]  = fmaf(fv, w0.w, acc[3]);
        acc[4]  = fmaf(fv, w1.x, acc[4]);  acc[5]  = fmaf(fv, w1.y, acc[5]);
        acc[6]  = fmaf(fv, w1.z, acc[6]);  acc[7]  = fmaf(fv, w1.w, acc[7]);
        acc[8]  = fmaf(fv, w2.x, acc[8]);  acc[9]  = fmaf(fv, w2.y, acc[9]);
        acc[10] = fmaf(fv, w2.z, acc[10]); acc[11] = fmaf(fv, w2.w, acc[11]);
        acc[12] = fmaf(fv, w3.x, acc[12]); acc[13] = fmaf(fv, w3.y, acc[13]);
        acc[14] = fmaf(fv, w3.z, acc[14]); acc[15] = fmaf(fv, w3.w, acc[15]);
      }
    }
    float* yo = &Y2[(size_t)i*C2 + oc];
    float4 o0 = {acc[0], acc[1], acc[2], acc[3]};
    float4 o1 = {acc[4], acc[5], acc[6], acc[7]};
    float4 o2 = {acc[8], acc[9], acc[10], acc[11]};
    float4 o3 = {acc[12], acc[13], acc[14], acc[15]};
    *(float4*)&yo[0] = o0; *(float4*)&yo[4] = o1;
    *(float4*)&yo[8] = o2; *(float4*)&yo[12] = o3;
  }
}

// ---------------- finalize top scale: vf + coors ----------------
__global__ __launch_bounds__(BLK) void k_fin_top(const float* __restrict__ seg2,
    const int* __restrict__ uniq, const int* __restrict__ cnt,
    const int* __restrict__ Up, float* __restrict__ vf, float* __restrict__ coors) {
  int idx = blockIdx.x * BLK + threadIdx.x;
  int r = idx >> 5;
  int cc = (idx & 31) << 2;
  if (r >= NPTS) return;
  int U = *Up;
  float4 o = {0.f, 0.f, 0.f, 0.f};
  if (r < U) {
    int lin = uniq[r];
    float ic = 1.0f / (float)cnt[lin];
    float4 s = *(const float4*)&seg2[(size_t)r*128 + cc];
    o.x = s.x*ic; o.y = s.y*ic; o.z = s.z*ic; o.w = s.w*ic;
  }
  *(float4*)&vf[(size_t)r*128 + cc] = o;
  if (cc == 0) {
    float4 co;
    if (r < U) {
      int lin = uniq[r];
      int x = lin % TGX; int t = lin / TGX;
      int y = t % TGY;   t /= TGY;
      int z = t % TGZ;   int b = t / TGZ;
      co.x = (float)b; co.y = (float)z; co.z = (float)y; co.w = (float)x;
    } else {
      co.x = -1.f; co.y = -1.f; co.z = -1.f; co.w = -1.f;
    }
    *(float4*)&coors[(size_t)r*4] = co;
  }
}

// ---------------- merge sub-scale voxel means into top parents ----------------
__global__ __launch_bounds__(BLK) void k_merge(const float* __restrict__ seg2,
    const int* __restrict__ uniq, const int* __restrict__ cnt,
    const int* __restrict__ Up, const int* __restrict__ tcnt,
    const int* __restrict__ trank, float* __restrict__ acc, int* __restrict__ mc,
    int gx, int gy, int gz, int factor) {
  int idx = blockIdx.x * BLK + threadIdx.x;
  int r = idx >> 4;
  int cc = (idx & 15) << 2;
  if (r >= *Up) return;
  int lin = uniq[r];
  int x = lin % gx; int t = lin / gx;
  int y = t % gy;   t /= gy;
  int z = t % gz;   int b = t / gz;
  int parent = ((b*TGZ + z/factor)*TGY + y/factor)*TGX + x/factor;
  if (tcnt[parent] <= 0) return;
  int pos = trank[parent];
  float ic = 1.0f / (float)cnt[lin];
  float4 s = *(const float4*)&seg2[(size_t)r*64 + cc];
  atomicAdd(&acc[(size_t)pos*64 + cc + 0], s.x*ic);
  atomicAdd(&acc[(size_t)pos*64 + cc + 1], s.y*ic);
  atomicAdd(&acc[(size_t)pos*64 + cc + 2], s.z*ic);
  atomicAdd(&acc[(size_t)pos*64 + cc + 3], s.w*ic);
  if (cc == 0) atomicAdd(&mc[pos], 1);
}

__global__ __launch_bounds__(BLK) void k_wmerged(const float* __restrict__ macc,
    const float* __restrict__ lacc, const int* __restrict__ mcm,
    const int* __restrict__ mcl, const int* __restrict__ Up,
    float* __restrict__ out) {
  int idx = blockIdx.x * BLK + threadIdx.x;
  int r = idx >> 5;
  int cc = (idx & 31) << 2;
  if (r >= NPTS) return;
  float4 o = {0.f, 0.f, 0.f, 0.f};
  if (r < *Up) {
    if (cc < 64) {
      float ic = 1.0f / fmaxf((float)mcm[r], 1.f);
      float4 s = *(const float4*)&macc[(size_t)r*64 + cc];
      o.x = s.x*ic; o.y = s.y*ic; o.z = s.z*ic; o.w = s.w*ic;
    } else {
      float ic = 1.0f / fmaxf((float)mcl[r], 1.f);
      float4 s = *(const float4*)&lacc[(size_t)r*64 + cc - 64];
      o.x = s.x*ic; o.y = s.y*ic; o.z = s.z*ic; o.w = s.w*ic;
    }
  }
  *(float4*)&out[(size_t)r*128 + cc] = o;
}

// ---------------- one full VFE scale ----------------
template<int C1>
static void run_vfe(hipStream_t stream, const float* pts,
    int G, int gx, int gy, int gz, float vx, float vy, float vz,
    const float* W1, const float* g1, const float* b1,
    const float* W2, const float* g2, const float* b2,
    int* cntg, int* rankg, int* uniq, int* bsum, int* U,
    float* sxyz, float* seg1, float* seg2, float* stats, float* coef,
    float* Y1, float* Y2, size_t seg1_bytes, size_t seg2_bytes) {
  constexpr int C2 = 2 * C1;
  (void)hipMemsetAsync(cntg, 0, (size_t)G * 4, stream);
  k_count<<<NPTS/BLK, BLK, 0, stream>>>(pts, cntg, gx, gy, gz, vx, vy, vz);
  int nb = (G + SCAN_CHUNK - 1) / SCAN_CHUNK;
  k_scan1<<<nb, BLK, 0, stream>>>(cntg, G, bsum);
  k_scan2<<<1, 1024, 0, stream>>>(bsum, nb, U);
  k_scan3<<<nb, BLK, 0, stream>>>(cntg, G, bsum, rankg, uniq);
  (void)hipMemsetAsync(sxyz, 0, (size_t)NPTS * 3 * sizeof(float), stream);
  k_xyzsum<<<NPTS/BLK, BLK, 0, stream>>>(pts, rankg, sxyz, gx, gy, gz, vx, vy, vz);
  k_y1<C1><<<NPTS/BLK, BLK, 0, stream>>>(pts, cntg, rankg, sxyz, W1, Y1, gx, gy, gz, vx, vy, vz);
  (void)hipMemsetAsync(stats, 0, 2 * C1 * sizeof(float), stream);
  k_colreduce<C1><<<128, BLK, 0, stream>>>(Y1, stats, 2048);
  k_bncoef<C1><<<1, C1, 0, stream>>>(stats, g1, b1, coef);
  (void)hipMemsetAsync(seg1, 0, seg1_bytes, stream);
  k_bnseg<C1, true><<<NPTS/BLK, BLK, 0, stream>>>(pts, Y1, coef, rankg, seg1, gx, gy, gz, vx, vy, vz);
  k_y2<C1><<<NPTS/BLK, BLK, 0, stream>>>(pts, Y1, seg1, cntg, rankg, W2, Y2, gx, gy, gz, vx, vy, vz);
  (void)hipMemsetAsync(stats, 0, 2 * C2 * sizeof(float), stream);
  k_colreduce<C2><<<128, BLK, 0, stream>>>(Y2, stats, 2048);
  k_bncoef<C2><<<1, C2, 0, stream>>>(stats, g2, b2, coef);
  (void)hipMemsetAsync(seg2, 0, seg2_bytes, stream);
  k_bnseg<C2, false><<<NPTS/BLK, BLK, 0, stream>>>(pts, Y2, coef, rankg, seg2, gx, gy, gz, vx, vy, vz);
}

extern "C" void kernel_launch(void* const* d_in, const int* in_sizes, int n_in,
                              void* d_out, int out_size, void* d_ws, size_t ws_size,
                              hipStream_t stream) {
  const float* pts = (const float*)d_in[0];
  const float* W1t = (const float*)d_in[2];
  const float* g1t = (const float*)d_in[3];
  const float* b1t = (const float*)d_in[4];
  const float* W2t = (const float*)d_in[5];
  const float* g2t = (const float*)d_in[6];
  const float* b2t = (const float*)d_in[7];
  const float* W1m = (const float*)d_in[8];
  const float* g1m = (const float*)d_in[9];
  const float* b1m = (const float*)d_in[10];
  const float* W2m = (const float*)d_in[11];
  const float* g2m = (const float*)d_in[12];
  const float* b2m = (const float*)d_in[13];
  const float* W1l = (const float*)d_in[14];
  const float* g1l = (const float*)d_in[15];
  const float* b1l = (const float*)d_in[16];
  const float* W2l = (const float*)d_in[17];
  const float* g2l = (const float*)d_in[18];
  const float* b2l = (const float*)d_in[19];

  float* out = (float*)d_out;
  float* vf = out;                              // N x 128
  float* mg = out + (size_t)NPTS * 128;         // N x 128 (also used as scratch)
  float* co = out + (size_t)NPTS * 256;         // N x 4

  const int G_TOP = 2*1*200*176;     // 70,400
  const int G_MED = 2*2*400*352;     // 1,126,400
  const int G_LOW = 2*4*800*704;     // 4,505,600

  char* w = (char*)d_ws;
  size_t off = 0;
  auto alloc = [&](size_t bytes) -> void* {
    void* p = w + off;
    off = (off + bytes + 1023) & ~(size_t)1023;
    return p;
  };
  int*   top_cnt  = (int*)alloc((size_t)G_TOP * 4);
  int*   top_rank = (int*)alloc((size_t)G_TOP * 4);
  int*   big_cnt  = (int*)alloc((size_t)G_LOW * 4);
  int*   big_rank = (int*)alloc((size_t)G_LOW * 4);
  int*   uniq     = (int*)alloc((size_t)NPTS * 4);
  float* sxyz     = (float*)alloc((size_t)NPTS * 3 * 4);
  float* seg1     = (float*)alloc((size_t)NPTS * 32 * 4);   // covers top 70400*64 too
  float* seg2     = (float*)alloc((size_t)NPTS * 64 * 4);   // covers top 70400*128 too
  float* macc     = (float*)alloc((size_t)G_TOP * 64 * 4);
  float* lacc     = (float*)alloc((size_t)G_TOP * 64 * 4);
  int*   mcm      = (int*)alloc((size_t)G_TOP * 4);
  int*   mcl      = (int*)alloc((size_t)G_TOP * 4);
  float* stats    = (float*)alloc(2 * 128 * 4);
  float* coef     = (float*)alloc(2 * 128 * 4);
  int*   bsum     = (int*)alloc(1024 * 4);
  int*   Utop     = (int*)alloc(64);
  int*   Usub     = (int*)alloc(64);
  (void)in_sizes; (void)n_in; (void)out_size; (void)ws_size;

  // ---- TOP scale (C1=64, C2=128). y1 scratch in merged region, y2 in vf region.
  run_vfe<64>(stream, pts, G_TOP, 176, 200, 1, 0.4f, 0.4f, 4.0f,
              W1t, g1t, b1t, W2t, g2t, b2t,
              top_cnt, top_rank, uniq, bsum, Utop,
              sxyz, seg1, seg2, stats, coef,
              /*Y1*/ mg, /*Y2*/ vf,
              (size_t)G_TOP * 64 * 4, (size_t)G_TOP * 128 * 4);
  k_fin_top<<<(NPTS*32)/BLK, BLK, 0, stream>>>(seg2, uniq, top_cnt, Utop, vf, co);

  // ---- MED scale (C1=32, C2=64). y1 at mg+N*64, y2 at mg.
  run_vfe<32>(stream, pts, G_MED, 352, 400, 2, 0.2f, 0.2f, 2.0f,
              W1m, g1m, b1m, W2m, g2m, b2m,
              big_cnt, big_rank, uniq, bsum, Usub,
              sxyz, seg1, seg2, stats, coef,
              /*Y1*/ mg + (size_t)NPTS*64, /*Y2*/ mg,
              (size_t)NPTS * 32 * 4, (size_t)NPTS * 64 * 4);
  (void)hipMemsetAsync(macc, 0, (size_t)G_TOP * 64 * 4, stream);
  (void)hipMemsetAsync(mcm, 0, (size_t)G_TOP * 4, stream);
  k_merge<<<(NPTS*16)/BLK, BLK, 0, stream>>>(seg2, uniq, big_cnt, Usub,
      top_cnt, top_rank, macc, mcm, 352, 400, 2, 2);

  // ---- LOW scale (C1=32, C2=64).
  run_vfe<32>(stream, pts, G_LOW, 704, 800, 4, 0.1f, 0.1f, 1.0f,
              W1l, g1l, b1l, W2l, g2l, b2l,
              big_cnt, big_rank, uniq, bsum, Usub,
              sxyz, seg1, seg2, stats, coef,
              /*Y1*/ mg + (size_t)NPTS*64, /*Y2*/ mg,
              (size_t)NPTS * 32 * 4, (size_t)NPTS * 64 * 4);
  (void)hipMemsetAsync(lacc, 0, (size_t)G_TOP * 64 * 4, stream);
  (void)hipMemsetAsync(mcl, 0, (size_t)G_TOP * 4, stream);
  k_merge<<<(NPTS*16)/BLK, BLK, 0, stream>>>(seg2, uniq, big_cnt, Usub,
      top_cnt, top_rank, lacc, mcl, 704, 800, 4, 4);

  // ---- final merged write
  k_wmerged<<<(NPTS*32)/BLK, BLK, 0, stream>>>(macc, lacc, mcm, mcl, Utop, mg);
}

// Round 2
// 1944.155 us; speedup vs baseline: 3.8008x; 3.8008x over previous
//
#include <hip/hip_runtime.h>
#include <cstdint>
#include <cstddef>

#define NPTS 262144
#define BLK 256
#define TGX 176
#define TGY 200
#define TGZ 1

#define SCAN_ITEMS 32
#define SCAN_CHUNK (BLK*SCAN_ITEMS)

// ---------------- voxel coord helpers ----------------
__device__ __forceinline__ void pcoords(float x, float y, float z,
    float vx, float vy, float vz, int gx, int gy, int gz,
    int& cx, int& cy, int& cz) {
  cx = (int)floorf((x - 0.0f)  / vx);
  cy = (int)floorf((y + 40.0f) / vy);
  cz = (int)floorf((z + 3.0f)  / vz);
  cx = min(max(cx, 0), gx - 1);
  cy = min(max(cy, 0), gy - 1);
  cz = min(max(cz, 0), gz - 1);
}

// ---------------- pass 1: dense count grid ----------------
__global__ __launch_bounds__(BLK) void k_count(const float* __restrict__ pts,
    int* __restrict__ cnt, int gx, int gy, int gz, float vx, float vy, float vz) {
  int i = blockIdx.x * BLK + threadIdx.x;
  if (i >= NPTS) return;
  float b = pts[i*5+0], x = pts[i*5+1], y = pts[i*5+2], z = pts[i*5+3];
  int cx, cy, cz; pcoords(x, y, z, vx, vy, vz, gx, gy, gz, cx, cy, cz);
  int lin = (((int)b * gz + cz) * gy + cy) * gx + cx;
  atomicAdd(&cnt[lin], 1);
}

// ---------------- occupancy+count scan (3 phases) ----------------
__global__ __launch_bounds__(BLK) void k_scan1(const int* __restrict__ cnt, int G,
                                               int2* __restrict__ bsum) {
  int base = blockIdx.x * SCAN_CHUNK + threadIdx.x * SCAN_ITEMS;
  int so = 0, sp = 0;
  #pragma unroll
  for (int k = 0; k < SCAN_ITEMS; k++) {
    int j = base + k;
    if (j < G) { int c = cnt[j]; if (c > 0) { so++; sp += c; } }
  }
  __shared__ int sho[BLK], shp[BLK];
  sho[threadIdx.x] = so; shp[threadIdx.x] = sp; __syncthreads();
  for (int off = BLK/2; off > 0; off >>= 1) {
    if (threadIdx.x < off) {
      sho[threadIdx.x] += sho[threadIdx.x + off];
      shp[threadIdx.x] += shp[threadIdx.x + off];
    }
    __syncthreads();
  }
  if (threadIdx.x == 0) { int2 v; v.x = sho[0]; v.y = shp[0]; bsum[blockIdx.x] = v; }
}

__global__ __launch_bounds__(1024) void k_scan2(int2* __restrict__ bsum, int nb,
                                                int* __restrict__ U) {
  __shared__ int so[1024], sp[1024];
  int t = threadIdx.x;
  int vo = 0, vp = 0;
  if (t < nb) { int2 v = bsum[t]; vo = v.x; vp = v.y; }
  so[t] = vo; sp[t] = vp; __syncthreads();
  for (int off = 1; off < 1024; off <<= 1) {
    int ao = (t >= off) ? so[t - off] : 0;
    int ap = (t >= off) ? sp[t - off] : 0;
    __syncthreads();
    so[t] += ao; sp[t] += ap;
    __syncthreads();
  }
  if (t < nb) { int2 e; e.x = so[t] - vo; e.y = sp[t] - vp; bsum[t] = e; }
  if (t == 0) *U = so[1023];
}

__global__ __launch_bounds__(BLK) void k_scan3(const int* __restrict__ cnt, int G,
    const int2* __restrict__ bsum, int* __restrict__ rank,
    int* __restrict__ uniq, int* __restrict__ woff) {
  int base = blockIdx.x * SCAN_CHUNK + threadIdx.x * SCAN_ITEMS;
  int so = 0, sp = 0;
  #pragma unroll
  for (int k = 0; k < SCAN_ITEMS; k++) {
    int j = base + k;
    if (j < G) { int c = cnt[j]; if (c > 0) { so++; sp += c; } }
  }
  __shared__ int sho[BLK], shp[BLK];
  sho[threadIdx.x] = so; shp[threadIdx.x] = sp; __syncthreads();
  for (int off = 1; off < BLK; off <<= 1) {
    int ao = (threadIdx.x >= off) ? sho[threadIdx.x - off] : 0;
    int ap = (threadIdx.x >= off) ? shp[threadIdx.x - off] : 0;
    __syncthreads();
    sho[threadIdx.x] += ao; shp[threadIdx.x] += ap;
    __syncthreads();
  }
  int2 bb = bsum[blockIdx.x];
  int ro = bb.x + sho[threadIdx.x] - so;
  int po = bb.y + shp[threadIdx.x] - sp;
  for (int k = 0; k < SCAN_ITEMS; k++) {
    int j = base + k;
    if (j < G) {
      int c = cnt[j];
      if (c > 0) { rank[j] = ro; uniq[ro] = j; woff[ro] = po; ro++; po += c; }
    }
  }
}

// ---------------- counting-sort scatter ----------------
__global__ __launch_bounds__(BLK) void k_scatter(const float* __restrict__ pts,
    const int* __restrict__ rank, int* __restrict__ woff,
    float4* __restrict__ srt, int* __restrict__ jrank,
    int gx, int gy, int gz, float vx, float vy, float vz) {
  int i = blockIdx.x * BLK + threadIdx.x;
  if (i >= NPTS) return;
  float b = pts[i*5+0], x = pts[i*5+1], y = pts[i*5+2], z = pts[i*5+3], it = pts[i*5+4];
  int cx, cy, cz; pcoords(x, y, z, vx, vy, vz, gx, gy, gz, cx, cy, cz);
  int lin = (((int)b * gz + cz) * gy + cy) * gx + cx;
  int r = rank[lin];
  int j = atomicAdd(&woff[r], 1);
  float4 p; p.x = x; p.y = y; p.z = z; p.w = it;
  srt[j] = p;
  jrank[j] = r;
}

// ---------------- per-voxel xyz mean (contiguous reduce) ----------------
__global__ __launch_bounds__(BLK) void k_vox1(const float4* __restrict__ srt,
    const int* __restrict__ uniq, const int* __restrict__ cnt,
    const int* __restrict__ woff, const int* __restrict__ Up,
    float4* __restrict__ vmean) {
  int r = blockIdx.x * BLK + threadIdx.x;
  if (r >= *Up) return;
  int lin = uniq[r];
  int len = cnt[lin];
  int base = woff[r] - len;
  float sx = 0.f, sy = 0.f, sz = 0.f;
  for (int k = 0; k < len; k++) {
    float4 p = srt[base + k];
    sx += p.x; sy += p.y; sz += p.z;
  }
  float il = 1.0f / (float)len;
  float4 o; o.x = sx*il; o.y = sy*il; o.z = sz*il; o.w = il;
  vmean[r] = o;
}

// ---------------- layer 1 matmul: feats(10) @ W1 -> Y (N x C1, sorted) -------
template<int C1>
__global__ __launch_bounds__(BLK) void k_y1(const float4* __restrict__ srt,
    const int* __restrict__ jrank, const float4* __restrict__ vmean,
    const float* __restrict__ W1, float* __restrict__ Y,
    int gx, int gy, int gz, float vx, float vy, float vz) {
  __shared__ float w[10*C1];
  for (int t = threadIdx.x; t < 10*C1; t += BLK) w[t] = W1[t];
  __syncthreads();
  int i = blockIdx.x * BLK + threadIdx.x;
  if (i >= NPTS) return;
  float4 p = srt[i];
  int r = jrank[i];
  float4 vm = vmean[r];
  int cx, cy, cz; pcoords(p.x, p.y, p.z, vx, vy, vz, gx, gy, gz, cx, cy, cz);
  float f[10];
  f[0] = p.x; f[1] = p.y; f[2] = p.z; f[3] = p.w;
  f[4] = p.x - vm.x;
  f[5] = p.y - vm.y;
  f[6] = p.z - vm.z;
  f[7] = p.x - (0.0f   + (cx + 0.5f)*vx);
  f[8] = p.y - (-40.0f + (cy + 0.5f)*vy);
  f[9] = p.z - (-3.0f  + (cz + 0.5f)*vz);
  float* yo = &Y[(size_t)i*C1];
  #pragma unroll
  for (int o = 0; o < C1; o += 4) {
    float a0=0.f, a1=0.f, a2=0.f, a3=0.f;
    #pragma unroll
    for (int k = 0; k < 10; k++) {
      float fv = f[k];
      const float* wr = &w[k*C1 + o];
      a0 = fmaf(fv, wr[0], a0); a1 = fmaf(fv, wr[1], a1);
      a2 = fmaf(fv, wr[2], a2); a3 = fmaf(fv, wr[3], a3);
    }
    float4 v = {a0, a1, a2, a3};
    *(float4*)&yo[o] = v;
  }
}

// ---------------- column sum/sumsq reduction ----------------
template<int C>
__global__ __launch_bounds__(BLK) void k_colreduce(const float* __restrict__ Y,
    float* __restrict__ stats, int rowsPerBlock) {
  constexpr int G = BLK / C;
  int c = threadIdx.x & (C - 1);
  int g = threadIdx.x / C;
  int i0 = blockIdx.x * rowsPerBlock;
  float s = 0.f, q = 0.f;
  for (int rr = g; rr < rowsPerBlock; rr += G) {
    float v = Y[(size_t)(i0 + rr)*C + c];
    s += v; q += v*v;
  }
  __shared__ float ss[BLK], sq[BLK];
  ss[threadIdx.x] = s; sq[threadIdx.x] = q;
  __syncthreads();
  for (int off = BLK/2; off >= C; off >>= 1) {
    if (threadIdx.x < off) {
      ss[threadIdx.x] += ss[threadIdx.x + off];
      sq[threadIdx.x] += sq[threadIdx.x + off];
    }
    __syncthreads();
  }
  if (threadIdx.x < C) {
    atomicAdd(&stats[c], ss[threadIdx.x]);
    atomicAdd(&stats[C + c], sq[threadIdx.x]);
  }
}

template<int C>
__global__ void k_bncoef(const float* __restrict__ stats, const float* __restrict__ g,
                         const float* __restrict__ b, float* __restrict__ coef) {
  int c = threadIdx.x;
  if (c >= C) return;
  float mu  = stats[c] * (1.0f / NPTS);
  float var = stats[C + c] * (1.0f / NPTS) - mu*mu;
  float sc  = g[c] * (1.0f / sqrtf(var + 1e-3f));
  coef[c]     = sc;
  coef[C + c] = fmaf(-mu, sc, b[c]);
}

// -------- BN+ReLU (optionally in-place H) + per-voxel mean (contiguous) -----
template<int C, bool WRITE_H>
__global__ __launch_bounds__(BLK) void k_hseg(float* __restrict__ Y,
    const float* __restrict__ coef, const int* __restrict__ uniq,
    const int* __restrict__ cnt, const int* __restrict__ woff,
    const int* __restrict__ Up, float* __restrict__ outm) {
  __shared__ float sc[C], sb[C];
  for (int t = threadIdx.x; t < C; t += BLK) { sc[t] = coef[t]; sb[t] = coef[C + t]; }
  __syncthreads();
  constexpr int QPB = C/4;
  int tid = blockIdx.x * BLK + threadIdx.x;
  int r = tid / QPB;
  int q = tid % QPB;
  if (r >= *Up) return;
  int lin = uniq[r];
  int len = cnt[lin];
  int base = woff[r] - len;
  int c0 = q * 4;
  float s0 = sc[c0+0], s1 = sc[c0+1], s2 = sc[c0+2], s3 = sc[c0+3];
  float o0 = sb[c0+0], o1 = sb[c0+1], o2 = sb[c0+2], o3 = sb[c0+3];
  float a0=0.f, a1=0.f, a2=0.f, a3=0.f;
  for (int k = 0; k < len; k++) {
    float* yp = &Y[(size_t)(base + k)*C + c0];
    float4 v = *(float4*)yp;
    float h0 = fmaxf(fmaf(v.x, s0, o0), 0.f);
    float h1 = fmaxf(fmaf(v.y, s1, o1), 0.f);
    float h2 = fmaxf(fmaf(v.z, s2, o2), 0.f);
    float h3 = fmaxf(fmaf(v.w, s3, o3), 0.f);
    if (WRITE_H) { float4 hh = {h0, h1, h2, h3}; *(float4*)yp = hh; }
    a0 += h0; a1 += h1; a2 += h2; a3 += h3;
  }
  float il = 1.0f / (float)len;
  float4 o = {a0*il, a1*il, a2*il, a3*il};
  *(float4*)&outm[(size_t)r*C + c0] = o;
}

// ---------------- layer 2: [h1, segmean1] @ W2 -> Y2 (N x C2, sorted) -------
template<int C1>
__global__ __launch_bounds__(BLK) void k_y2(const float* __restrict__ H1,
    const float* __restrict__ seg1m, const int* __restrict__ jrank,
    const float* __restrict__ W2, float* __restrict__ Y2) {
  constexpr int C2 = 2 * C1;
  __shared__ float w[2*C1*C2];
  for (int t = threadIdx.x*4; t < 2*C1*C2; t += BLK*4)
    *(float4*)&w[t] = *(const float4*)&W2[t];
  __syncthreads();
  int i = blockIdx.x * BLK + threadIdx.x;
  if (i >= NPTS) return;
  int r = jrank[i];
  const float* h1row = &H1[(size_t)i*C1];
  const float* smrow = &seg1m[(size_t)r*C1];
  #pragma unroll 1
  for (int oc = 0; oc < C2; oc += 16) {
    float acc[16];
    #pragma unroll
    for (int j = 0; j < 16; j++) acc[j] = 0.f;
    for (int k = 0; k < C1; k += 4) {
      float4 a = *(const float4*)&h1row[k];
      float av[4] = {a.x, a.y, a.z, a.w};
      #pragma unroll
      for (int kk = 0; kk < 4; kk++) {
        const float* wr = &w[(k + kk)*C2 + oc];
        float4 w0 = *(float4*)&wr[0],  w1 = *(float4*)&wr[4];
        float4 w2 = *(float4*)&wr[8],  w3 = *(float4*)&wr[12];
        float fv = av[kk];
        acc[0]  = fmaf(fv, w0.x, acc[0]);  acc[1]  = fmaf(fv, w0.y, acc[1]);
        acc[2]  = fmaf(fv, w0.z, acc[2]);  acc[3]  = fmaf(fv, w0.w, acc[3]);
        acc[4]  = fmaf(fv, w1.x, acc[4]);  acc[5]  = fmaf(fv, w1.y, acc[5]);
        acc[6]  = fmaf(fv, w1.z, acc[6]);  acc[7]  = fmaf(fv, w1.w, acc[7]);
        acc[8]  = fmaf(fv, w2.x, acc[8]);  acc[9]  = fmaf(fv, w2.y, acc[9]);
        acc[10] = fmaf(fv, w2.z, acc[10]); acc[11] = fmaf(fv, w2.w, acc[11]);
        acc[12] = fmaf(fv, w3.x, acc[12]); acc[13] = fmaf(fv, w3.y, acc[13]);
        acc[14] = fmaf(fv, w3.z, acc[14]); acc[15] = fmaf(fv, w3.w, acc[15]);
      }
    }
    for (int k = 0; k < C1; k += 4) {
      float4 a = *(const float4*)&smrow[k];
      float av[4] = {a.x, a.y, a.z, a.w};
      #pragma unroll
      for (int kk = 0; kk < 4; kk++) {
        const float* wr = &w[(C1 + k + kk)*C2 + oc];
        float4 w0 = *(float4*)&wr[0],  w1 = *(float4*)&wr[4];
        float4 w2 = *(float4*)&wr[8],  w3 = *(float4*)&wr[12];
        float fv = av[kk];
        acc[0]  = fmaf(fv, w0.x, acc[0]);  acc[1]  = fmaf(fv, w0.y, acc[1]);
        acc[2]  = fmaf(fv, w0.z, acc[2]);  acc[3]  = fmaf(fv, w0.w, acc[3]);
        acc[4]  = fmaf(fv, w1.x, acc[4]);  acc[5]  = fmaf(fv, w1.y, acc[5]);
        acc[6]  = fmaf(fv, w1.z, acc[6]);  acc[7]  = fmaf(fv, w1.w, acc[7]);
        acc[8]  = fmaf(fv, w2.x, acc[8]);  acc[9]  = fmaf(fv, w2.y, acc[9]);
        acc[10] = fmaf(fv, w2.z, acc[10]); acc[11] = fmaf(fv, w2.w, acc[11]);
        acc[12] = fmaf(fv, w3.x, acc[12]); acc[13] = fmaf(fv, w3.y, acc[13]);
        acc[14] = fmaf(fv, w3.z, acc[14]); acc[15] = fmaf(fv, w3.w, acc[15]);
      }
    }
    float* yo = &Y2[(size_t)i*C2 + oc];
    float4 out0 = {acc[0], acc[1], acc[2], acc[3]};
    float4 out1 = {acc[4], acc[5], acc[6], acc[7]};
    float4 out2 = {acc[8], acc[9], acc[10], acc[11]};
    float4 out3 = {acc[12], acc[13], acc[14], acc[15]};
    *(float4*)&yo[0] = out0; *(float4*)&yo[4] = out1;
    *(float4*)&yo[8] = out2; *(float4*)&yo[12] = out3;
  }
}

// ---------------- finalize top scale: vf + coors ----------------
__global__ __launch_bounds__(BLK) void k_fin_top(const float* __restrict__ voxfeat,
    const int* __restrict__ uniq, const int* __restrict__ Up,
    float* __restrict__ vf, float* __restrict__ coors) {
  int idx = blockIdx.x * BLK + threadIdx.x;
  int r = idx >> 5;
  int cc = (idx & 31) << 2;
  if (r >= NPTS) return;
  int U = *Up;
  float4 o = {0.f, 0.f, 0.f, 0.f};
  if (r < U) o = *(const float4*)&voxfeat[(size_t)r*128 + cc];
  *(float4*)&vf[(size_t)r*128 + cc] = o;
  if (cc == 0) {
    float4 co;
    if (r < U) {
      int lin = uniq[r];
      int x = lin % TGX; int t = lin / TGX;
      int y = t % TGY;   t /= TGY;
      int z = t % TGZ;   int b = t / TGZ;
      co.x = (float)b; co.y = (float)z; co.z = (float)y; co.w = (float)x;
    } else {
      co.x = -1.f; co.y = -1.f; co.z = -1.f; co.w = -1.f;
    }
    *(float4*)&coors[(size_t)r*4] = co;
  }
}

// ------------- merge: build per-parent child-rank list (gather) -------------
__global__ __launch_bounds__(BLK) void k_clist(const int* __restrict__ tuniq,
    const int* __restrict__ Utp, const int* __restrict__ scnt,
    const int* __restrict__ srank, int* __restrict__ clist, int* __restrict__ mcnt,
    int gx, int gy, int gz, int f) {
  int r = blockIdx.x * BLK + threadIdx.x;
  if (r >= *Utp) return;
  int lin = tuniq[r];
  int x = lin % TGX; int t = lin / TGX;
  int y = t % TGY;   int b = t / TGY;   // TGZ == 1 so z == 0
  int m = 0;
  for (int cz = 0; cz < gz; cz++)
    for (int yy = y*f; yy < y*f + f; yy++)
      for (int xx = x*f; xx < x*f + f; xx++) {
        int cl = ((b*gz + cz)*gy + yy)*gx + xx;
        if (scnt[cl] > 0) clist[(size_t)r*64 + (m++)] = srank[cl];
      }
  mcnt[r] = m;
}

__global__ __launch_bounds__(BLK) void k_merge2(const float* __restrict__ voxfeat,
    const int* __restrict__ clist, const int* __restrict__ mcnt,
    const int* __restrict__ Utp, float* __restrict__ dest) {
  int idx = blockIdx.x * BLK + threadIdx.x;
  int r = idx >> 4;
  int q = idx & 15;
  if (r >= *Utp) return;
  int m = mcnt[r];
  float a0=0.f, a1=0.f, a2=0.f, a3=0.f;
  for (int t = 0; t < m; t++) {
    int cr = clist[(size_t)r*64 + t];
    float4 v = *(const float4*)&voxfeat[(size_t)cr*64 + q*4];
    a0 += v.x; a1 += v.y; a2 += v.z; a3 += v.w;
  }
  float inv = 1.0f / (float)max(m, 1);
  float4 o = {a0*inv, a1*inv, a2*inv, a3*inv};
  *(float4*)&dest[(size_t)r*64 + q*4] = o;
}

// ---------------- final merged compose + tail zero ----------------
__global__ __launch_bounds__(BLK) void k_compose(const float* __restrict__ maccm,
    const float* __restrict__ maccl, const int* __restrict__ Up,
    float* __restrict__ out) {
  int idx = blockIdx.x * BLK + threadIdx.x;
  int r = idx >> 5;
  int q = idx & 31;
  if (r >= NPTS || r >= *Up) return;
  float4 v = (q < 16) ? *(const float4*)&maccm[(size_t)r*64 + q*4]
                      : *(const float4*)&maccl[(size_t)r*64 + (q-16)*4];
  *(float4*)&out[(size_t)r*128 + q*4] = v;
}

__global__ __launch_bounds__(BLK) void k_zerotail(const int* __restrict__ Up,
    float* __restrict__ out) {
  int idx = blockIdx.x * BLK + threadIdx.x;
  int r = idx >> 5;
  int q = idx & 31;
  if (r >= NPTS || r < *Up) return;
  float4 z = {0.f, 0.f, 0.f, 0.f};
  *(float4*)&out[(size_t)r*128 + q*4] = z;
}

// ---------------- one full VFE scale ----------------
template<int C1>
static void run_vfe(hipStream_t stream, const float* pts,
    int G, int gx, int gy, int gz, float vx, float vy, float vz, int UB,
    const float* W1, const float* g1, const float* b1,
    const float* W2, const float* g2, const float* b2,
    int* cntg, int* rankg, int* uniq, int* woff, int2* bsum, int* U,
    float4* srt, int* jrank, float4* vmean,
    float* seg1m, float* voxfeat, float* stats, float* coef,
    float* Y1, float* Y2) {
  constexpr int C2 = 2 * C1;
  (void)hipMemsetAsync(cntg, 0, (size_t)G * 4, stream);
  k_count<<<NPTS/BLK, BLK, 0, stream>>>(pts, cntg, gx, gy, gz, vx, vy, vz);
  int nb = (G + SCAN_CHUNK - 1) / SCAN_CHUNK;
  k_scan1<<<nb, BLK, 0, stream>>>(cntg, G, bsum);
  k_scan2<<<1, 1024, 0, stream>>>(bsum, nb, U);
  k_scan3<<<nb, BLK, 0, stream>>>(cntg, G, bsum, rankg, uniq, woff);
  k_scatter<<<NPTS/BLK, BLK, 0, stream>>>(pts, rankg, woff, srt, jrank, gx, gy, gz, vx, vy, vz);
  k_vox1<<<(UB + BLK - 1)/BLK, BLK, 0, stream>>>(srt, uniq, cntg, woff, U, vmean);
  k_y1<C1><<<NPTS/BLK, BLK, 0, stream>>>(srt, jrank, vmean, W1, Y1, gx, gy, gz, vx, vy, vz);
  (void)hipMemsetAsync(stats, 0, 2 * C1 * sizeof(float), stream);
  k_colreduce<C1><<<128, BLK, 0, stream>>>(Y1, stats, 2048);
  k_bncoef<C1><<<1, C1, 0, stream>>>(stats, g1, b1, coef);
  k_hseg<C1, true><<<((size_t)UB*(C1/4) + BLK - 1)/BLK, BLK, 0, stream>>>(
      Y1, coef, uniq, cntg, woff, U, seg1m);
  k_y2<C1><<<NPTS/BLK, BLK, 0, stream>>>(Y1, seg1m, jrank, W2, Y2);
  (void)hipMemsetAsync(stats, 0, 2 * C2 * sizeof(float), stream);
  k_colreduce<C2><<<128, BLK, 0, stream>>>(Y2, stats, 2048);
  k_bncoef<C2><<<1, C2, 0, stream>>>(stats, g2, b2, coef);
  k_hseg<C2, false><<<((size_t)UB*(C2/4) + BLK - 1)/BLK, BLK, 0, stream>>>(
      Y2, coef, uniq, cntg, woff, U, voxfeat);
}

extern "C" void kernel_launch(void* const* d_in, const int* in_sizes, int n_in,
                              void* d_out, int out_size, void* d_ws, size_t ws_size,
                              hipStream_t stream) {
  const float* pts = (const float*)d_in[0];
  const float* W1t = (const float*)d_in[2];
  const float* g1t = (const float*)d_in[3];
  const float* b1t = (const float*)d_in[4];
  const float* W2t = (const float*)d_in[5];
  const float* g2t = (const float*)d_in[6];
  const float* b2t = (const float*)d_in[7];
  const float* W1m = (const float*)d_in[8];
  const float* g1m = (const float*)d_in[9];
  const float* b1m = (const float*)d_in[10];
  const float* W2m = (const float*)d_in[11];
  const float* g2m = (const float*)d_in[12];
  const float* b2m = (const float*)d_in[13];
  const float* W1l = (const float*)d_in[14];
  const float* g1l = (const float*)d_in[15];
  const float* b1l = (const float*)d_in[16];
  const float* W2l = (const float*)d_in[17];
  const float* g2l = (const float*)d_in[18];
  const float* b2l = (const float*)d_in[19];

  float* out = (float*)d_out;
  float* vf = out;                              // N x 128
  float* mg = out + (size_t)NPTS * 128;         // N x 128 (also scratch)
  float* co = out + (size_t)NPTS * 256;         // N x 4

  const int G_TOP = 2*1*200*176;     // 70,400
  const int G_MED = 2*2*400*352;     // 1,126,400
  const int G_LOW = 2*4*800*704;     // 4,505,600

  char* w = (char*)d_ws;
  size_t off = 0;
  auto alloc = [&](size_t bytes) -> void* {
    void* p = w + off;
    off = (off + bytes + 1023) & ~(size_t)1023;
    return p;
  };
  int*    top_cnt  = (int*)alloc((size_t)G_TOP * 4);
  int*    top_rank = (int*)alloc((size_t)G_TOP * 4);
  int*    top_uniq = (int*)alloc((size_t)G_TOP * 4);
  int*    big_cnt  = (int*)alloc((size_t)G_LOW * 4);
  int*    big_rank = (int*)alloc((size_t)G_LOW * 4);
  int*    sub_uniq = (int*)alloc((size_t)NPTS * 4);
  int*    woff     = (int*)alloc((size_t)NPTS * 4);
  float4* srt      = (float4*)alloc((size_t)NPTS * 16);
  int*    jrank    = (int*)alloc((size_t)NPTS * 4);
  float4* vmean    = (float4*)alloc((size_t)NPTS * 16);
  float*  seg1m    = (float*)alloc((size_t)NPTS * 32 * 4);   // also clist (18MB<33MB)
  float*  voxfeat  = (float*)alloc((size_t)NPTS * 64 * 4);
  int*    mcnt     = (int*)alloc((size_t)G_TOP * 4);
  float*  maccl    = (float*)alloc((size_t)G_TOP * 64 * 4);
  float*  stats    = (float*)alloc(2 * 128 * 4);
  float*  coef     = (float*)alloc(2 * 128 * 4);
  int2*   bsum     = (int2*)alloc(1024 * 8);
  int*    Utop     = (int*)alloc(64);
  int*    Usub     = (int*)alloc(64);
  (void)in_sizes; (void)n_in; (void)out_size; (void)ws_size;

  float* maccm = mg + (size_t)NPTS * 96;   // lives in mg region rows [0.75N, N)
  int*   clist = (int*)seg1m;              // alias: dead between hseg2 and next scale's hseg1

  // ---- TOP scale (C1=64, C2=128). Y1 in mg region, Y2 in vf region.
  run_vfe<64>(stream, pts, G_TOP, 176, 200, 1, 0.4f, 0.4f, 4.0f, G_TOP,
              W1t, g1t, b1t, W2t, g2t, b2t,
              top_cnt, top_rank, top_uniq, woff, bsum, Utop,
              srt, jrank, vmean, seg1m, voxfeat, stats, coef,
              /*Y1*/ mg, /*Y2*/ vf);
  k_fin_top<<<(NPTS*32)/BLK, BLK, 0, stream>>>(voxfeat, top_uniq, Utop, vf, co);

  // ---- MED scale (C1=32, C2=64). Y1 at mg[0,32N), Y2 at mg[32N,96N).
  run_vfe<32>(stream, pts, G_MED, 352, 400, 2, 0.2f, 0.2f, 2.0f, NPTS,
              W1m, g1m, b1m, W2m, g2m, b2m,
              big_cnt, big_rank, sub_uniq, woff, bsum, Usub,
              srt, jrank, vmean, seg1m, voxfeat, stats, coef,
              /*Y1*/ mg, /*Y2*/ mg + (size_t)NPTS*32);
  k_clist<<<(G_TOP + BLK - 1)/BLK, BLK, 0, stream>>>(top_uniq, Utop, big_cnt, big_rank,
      clist, mcnt, 352, 400, 2, 2);
  k_merge2<<<((size_t)G_TOP*16 + BLK - 1)/BLK, BLK, 0, stream>>>(voxfeat, clist, mcnt,
      Utop, maccm);

  // ---- LOW scale (C1=32, C2=64). Same scratch regions (maccm untouched).
  run_vfe<32>(stream, pts, G_LOW, 704, 800, 4, 0.1f, 0.1f, 1.0f, NPTS,
              W1l, g1l, b1l, W2l, g2l, b2l,
              big_cnt, big_rank, sub_uniq, woff, bsum, Usub,
              srt, jrank, vmean, seg1m, voxfeat, stats, coef,
              /*Y1*/ mg, /*Y2*/ mg + (size_t)NPTS*32);
  k_clist<<<(G_TOP + BLK - 1)/BLK, BLK, 0, stream>>>(top_uniq, Utop, big_cnt, big_rank,
      clist, mcnt, 704, 800, 4, 4);
  k_merge2<<<((size_t)G_TOP*16 + BLK - 1)/BLK, BLK, 0, stream>>>(voxfeat, clist, mcnt,
      Utop, maccl);

  // ---- final merged write: rows < U from macc buffers, then zero the tail.
  k_compose<<<(NPTS*32)/BLK, BLK, 0, stream>>>(maccm, maccl, Utop, mg);
  k_zerotail<<<(NPTS*32)/BLK, BLK, 0, stream>>>(Utop, mg);
}